// Round 9
// baseline (319.133 us; speedup 1.0000x reference)
//
#include <hip/hip_runtime.h>

#define S_LEN 2048
#define D_DIM 1024
#define NB    4
#define NH    16
#define HDIM  64
#define QSCL  0.18033688011112042f   // 0.125 * log2(e): softmax via exp2

typedef float  f32x4  __attribute__((ext_vector_type(4)));
typedef __bf16 bf16x4 __attribute__((ext_vector_type(4)));
typedef __bf16 bf16x8 __attribute__((ext_vector_type(8)));

static __device__ __forceinline__ f32x4 mfma16(bf16x8 a, bf16x8 b, f32x4 c) {
  return __builtin_amdgcn_mfma_f32_16x16x32_bf16(a, b, c, 0, 0, 0);
}
static __device__ __forceinline__ bf16x4 cvt4(f32x4 v) {
  return __builtin_convertvector(v, bf16x4);
}
// async 16B/lane global->LDS; LDS dest = wave-uniform base + lane*16
static __device__ __forceinline__ void cp16(const void* g, void* l) {
  __builtin_amdgcn_global_load_lds(
      (const __attribute__((address_space(1))) unsigned int*)g,
      (__attribute__((address_space(3))) unsigned int*)l, 16, 0, 0);
}

// ---------------------------------------------------------------------------
// Fused fp32 -> bf16 pre-convert for activations AND weights (R5-proven).
// grid = (8192, 4): y<3 -> q/k/v (8192 blocks x 1024 elems);
//                   y=3 -> Wq|Wk|Wv|Wo (x<4096, 1024 blocks each).
// ---------------------------------------------------------------------------
__global__ __launch_bounds__(256) void conv_all(
    const float* __restrict__ q, const float* __restrict__ k,
    const float* __restrict__ v,
    const float* __restrict__ Wq, const float* __restrict__ Wk,
    const float* __restrict__ Wv, const float* __restrict__ Wo,
    __bf16* __restrict__ abf, __bf16* __restrict__ wbf)
{
  const int y = blockIdx.y;
  if (y < 3) {
    const float* src = (y == 0) ? q : (y == 1) ? k : v;
    size_t i = ((size_t)blockIdx.x * 256 + threadIdx.x) * 4;
    f32x4 x = *(const f32x4*)(src + i);
    *(bf16x4*)(abf + (size_t)y * ((size_t)NB * S_LEN * D_DIM) + i) = cvt4(x);
  } else {
    if (blockIdx.x >= 4096) return;
    const int w = blockIdx.x >> 10;             // which weight matrix
    const float* src = (w == 0) ? Wq : (w == 1) ? Wk : (w == 2) ? Wv : Wo;
    size_t i = ((size_t)(blockIdx.x & 1023) * 256 + threadIdx.x) * 4;
    f32x4 x = *(const f32x4*)(src + i);
    *(bf16x4*)(wbf + (size_t)w * (D_DIM * D_DIM) + i) = cvt4(x);
  }
}

// ---------------------------------------------------------------------------
// Shared epilogue for QKV projection: scatter to head layout.
// ---------------------------------------------------------------------------
static __device__ __forceinline__ void proj_epilogue(
    f32x4 (&acc)[4][4], int z, int mbase, int nbase, int wm, int wn,
    int l15, int quad, const float* bias,
    __bf16* qh, __bf16* kh, __bf16* vt)
{
  const float scl = (z == 0) ? QSCL : 1.0f;  // fold 1/sqrt(HD)*log2e into Q
#pragma unroll
  for (int mt = 0; mt < 4; ++mt)
#pragma unroll
    for (int nt = 0; nt < 4; ++nt) {
      int n = nbase + wn + nt * 16 + l15;
      int h = n >> 6, hd = n & 63;
      float bb = bias[n];
      f32x4 vv = acc[mt][nt];
#pragma unroll
      for (int r = 0; r < 4; ++r) vv[r] = (vv[r] + bb) * scl;
      bf16x4 pv = cvt4(vv);
      int m0 = mbase + wm + mt * 16 + quad * 4;
      int b = m0 >> 11, s0 = m0 & 2047;
      if (z == 2) {
        *(bf16x4*)(vt + ((size_t)((b * NH + h) * HDIM + hd)) * S_LEN + s0) = pv;
      } else {
        __bf16* out = (z == 0) ? qh : kh;
#pragma unroll
        for (int r = 0; r < 4; ++r)
          out[((size_t)(b * NH + h) * S_LEN + s0 + r) * HDIM + hd] = pv[r];
      }
    }
}

// ---------------------------------------------------------------------------
// QKV projection, pure-bf16: 128x128, BK=64, XOR-swizzled async staging.
// R8-measured: 61us, MfmaUtil 36%, FETCH 42.5MB, 0 conflicts (T1 confirmed).
// XCD-chunked swizzle: each XCD gets 192 contiguous wgs, (z, x, y-fastest).
// ---------------------------------------------------------------------------
__global__ __launch_bounds__(256, 4) void proj_bf16(
    const __bf16* __restrict__ abf, const __bf16* __restrict__ Wbf,
    const float* __restrict__ bq, const float* __restrict__ bk, const float* __restrict__ bv,
    __bf16* __restrict__ qh, __bf16* __restrict__ kh, __bf16* __restrict__ vt)
{
  const int lin = blockIdx.x + (blockIdx.y << 6) + (blockIdx.z << 9); // 0..1535
  const int wg  = (lin & 7) * 192 + (lin >> 3);
  const int z   = wg >> 9;            // 0..2
  const int rem = wg & 511;
  const int xg  = rem >> 3;           // 0..63
  const int yg  = rem & 7;            // 0..7

  const __bf16* A = abf + (size_t)z * ((size_t)NB * S_LEN * D_DIM);
  const __bf16* W = Wbf + (size_t)z * (D_DIM * D_DIM);
  const float* bias = (z == 0) ? bq : (z == 1) ? bk : bv;

  __shared__ __bf16 As[128 * 64];
  __shared__ __bf16 Bs[128 * 64];

  const int tid  = threadIdx.x;
  const int wave = tid >> 6;
  const int lane = tid & 63;
  const int l15  = lane & 15;
  const int quad = lane >> 4;
  const int mbase = xg * 128;
  const int nbase = yg * 128;
  const int wm = (wave & 1) * 64;
  const int wn = (wave >> 1) * 64;
  const int brow = lane >> 3;
  const int scol = ((lane & 7) ^ (brow & 7)) * 8;
  const int swz  = l15 & 7;

  f32x4 acc[4][4] = {};

  for (int kt = 0; kt < D_DIM; kt += 64) {
#pragma unroll
    for (int c = 0; c < 4; ++c) {
      int r = wave * 32 + c * 8 + brow;
      cp16(A + (size_t)(mbase + r) * D_DIM + kt + scol, As + r * 64);
      cp16(W + (size_t)(nbase + r) * D_DIM + kt + scol, Bs + r * 64);
    }
    __syncthreads();

#pragma unroll
    for (int k0 = 0; k0 < 2; ++k0) {
      bf16x8 af[4], bfr[4];
#pragma unroll
      for (int i = 0; i < 4; ++i) {
        int off = ((k0 * 4 + quad) ^ swz) * 8;
        af[i]  = *(const bf16x8*)(As + (wm + i * 16 + l15) * 64 + off);
        bfr[i] = *(const bf16x8*)(Bs + (wn + i * 16 + l15) * 64 + off);
      }
#pragma unroll
      for (int mt = 0; mt < 4; ++mt)
#pragma unroll
        for (int nt = 0; nt < 4; ++nt)
          acc[mt][nt] = mfma16(af[mt], bfr[nt], acc[mt][nt]);
    }
    __syncthreads();
  }

  proj_epilogue(acc, z, mbase, nbase, wm, wn, l15, quad, bias, qh, kh, vt);
}

// ---------------------------------------------------------------------------
// Flash attention: FOUR causal-balanced chunks/block, TRANSPOSE-FREE P.
// grid (8,64) = 512 blocks = 2/CU (launch_bounds(256,2): 256-reg cap, no
// spill risk — R6 lesson). Chunks {x, 31-x, x+8, 23-x}: 66 chunk-tiles per
// block, CONSTANT (perfect balance). vs the 2-chunk version this amortizes
// K/V staging AND the per-tile barrier+vmcnt drain over 2x the compute:
// staged bytes and barriers per chunk-tile drop 0.74 -> 0.43 (-42%).
// Pairs processed SEQUENTIALLY per tile (pair0 = {x, 31-x}, pair1 =
// {x+8, 23-x}) so sc[] is transient per pair: peak regs ~150 < 256.
// Pair1 skipped entirely for kt > 23-x (block-uniform). All other machinery
// (transpose-free permuted K-frag, conflict-free swizzles, dbuf 1 barrier/
// tile, setprio, XCD swizzle 8 bh/XCD) identical to the R8-proven kernel.
// ---------------------------------------------------------------------------
__global__ __launch_bounds__(256, 2) void attn_kernel(
    const __bf16* __restrict__ qh, const __bf16* __restrict__ kh,
    const __bf16* __restrict__ vt, __bf16* __restrict__ ao)
{
  __shared__ __bf16 Kb[2][64 * 64];
  __shared__ __bf16 Vb[2][64 * 64];

  // XCD-bijective swizzle: lin%8 == XCD; each XCD gets 8 complete bh.
  const int lin = blockIdx.x + (blockIdx.y << 3);      // 0..511
  const int xcd = lin & 7;
  const int idx = lin >> 3;                            // 0..63
  const int x   = idx & 7;                             // 0..7
  const int bh  = xcd * 8 + (idx >> 3);                // 8 bh per XCD

  const int qcs[4] = { x, 31 - x, x + 8, 23 - x };     // causal-balanced set
  const int last = 31 - x;

  const __bf16* qp = qh + (size_t)bh * S_LEN * HDIM;
  const __bf16* kp = kh + (size_t)bh * S_LEN * HDIM;
  const __bf16* vp = vt + (size_t)bh * HDIM * S_LEN;

  const int tid  = threadIdx.x;
  const int wave = tid >> 6;
  const int lane = tid & 63;
  const int l15  = lane & 15;
  const int quad = lane >> 4;
  const int w16  = wave * 16;
  const int srow = lane >> 3;
  const int swz  = l15 & 7;                            // K-read col swizzle
  const int vswz = ((l15 >> 3) << 2) | (l15 & 3);      // V-read col swizzle
  const int kr0  = ((l15 >> 2) << 3) | (l15 & 3);      // K-frag row base (perm)
  const int b = bh >> 4, h = bh & 15;

  // Q fragments for all 4 chunks (B-op layout: col=l15, k=quad*8+j)
  bf16x8 fq[4][2];
#pragma unroll
  for (int j = 0; j < 4; ++j) {
    const int qb = qcs[j] * 64;
    const __bf16* qrow = qp + (size_t)(qb + w16 + l15) * HDIM;
    fq[j][0] = *(const bf16x8*)(qrow + quad * 8);
    fq[j][1] = *(const bf16x8*)(qrow + 32 + quad * 8);
  }

  f32x4 accO[4][4] = {};
  float lp[4] = {0.f, 0.f, 0.f, 0.f};   // per-lane partial denom, qrow = l15

  // prologue: stage tile 0 into buffer 0.  h(row)=4*((row>>3)&1)+(row&3):
  // row = w16+8c+srow -> h = 4*(c&1) + (srow&3).
#pragma unroll
  for (int c = 0; c < 2; ++c) {
    int rb = w16 + c * 8;
    int sc2 = (((lane & 7) ^ (((c & 1) << 2) | (srow & 3)))) * 8;
    cp16(kp + (size_t)(rb + srow) * HDIM + sc2, &Kb[0][rb * 64]);
    cp16(vp + (size_t)(rb + srow) * S_LEN + sc2, &Vb[0][rb * 64]);
  }

  int cur = 0;
  for (int kt = 0; kt <= last; ++kt) {
    __syncthreads();   // drains own vmcnt -> buf[cur] staged; buf[cur^1] free

    if (kt < last) {   // stage kt+1 into the free buffer; hidden under compute
#pragma unroll
      for (int c = 0; c < 2; ++c) {
        int rb = w16 + c * 8;
        int sc2 = (((lane & 7) ^ (((c & 1) << 2) | (srow & 3)))) * 8;
        cp16(kp + (size_t)((kt + 1) * 64 + rb + srow) * HDIM + sc2,
             &Kb[cur ^ 1][rb * 64]);
        cp16(vp + (size_t)(rb + srow) * S_LEN + (kt + 1) * 64 + sc2,
             &Vb[cur ^ 1][rb * 64]);
      }
    }

    const __bf16* Kc = &Kb[cur][0];
    const __bf16* Vc = &Vb[cur][0];
    const bool skip1 = (kt > 23 - x);   // pair1 fully done (block-uniform)

#pragma unroll
    for (int p = 0; p < 2; ++p) {
      if (p == 1 && skip1) continue;
      const int ja = 2 * p, jb = 2 * p + 1;
      const bool actA = (kt <= qcs[ja]);   // short chunk of the pair; jb always active here

      // S^T = K Q^T with PERMUTED K-frag rows; K frag read once per pair
      f32x4 sc[2][4] = {};
      __builtin_amdgcn_s_setprio(1);
#pragma unroll
      for (int k0 = 0; k0 < 2; ++k0)
#pragma unroll
        for (int nt = 0; nt < 4; ++nt) {
          const int krow = kr0 + ((nt & 1) << 2) + ((nt >> 1) << 5);
          bf16x8 bk = *(const bf16x8*)(Kc + krow * 64 +
                                       (((k0 * 4 + quad) ^ swz) * 8));
          if (actA) sc[0][nt] = mfma16(bk, fq[ja][k0], sc[0][nt]);
          sc[1][nt] = mfma16(bk, fq[jb][k0], sc[1][nt]);
        }
      __builtin_amdgcn_s_setprio(0);

      // softmax -> PV A-frags, pure register (no transpose needed)
      bf16x8 pa[2][2];
#pragma unroll
      for (int jj = 0; jj < 2; ++jj) {
        if (jj == 0 && !actA) continue;   // uniform
        const int j = 2 * p + jj;
        const int qcj = qcs[j];
        f32x4 pf[4];
#pragma unroll
        for (int nt = 0; nt < 4; ++nt) {
#pragma unroll
          for (int r = 0; r < 4; ++r) pf[nt][r] = __builtin_amdgcn_exp2f(sc[jj][nt][r]);
          if (kt == qcj) {  // diag tile: causal mask (relabeled key)
#pragma unroll
            for (int r = 0; r < 4; ++r) {
              int key = ((nt >> 1) << 5) + (quad << 3) + ((nt & 1) << 2) + r;
              if (key > w16 + l15) pf[nt][r] = 0.f;
            }
          }
        }
        f32x4 lv = (pf[0] + pf[1]) + (pf[2] + pf[3]);
        lp[j] += (lv[0] + lv[1]) + (lv[2] + lv[3]);
        bf16x4 c0 = cvt4(pf[0]), c1 = cvt4(pf[1]), c2 = cvt4(pf[2]), c3 = cvt4(pf[3]);
        bf16x8 p0, p1;
        p0[0]=c0[0]; p0[1]=c0[1]; p0[2]=c0[2]; p0[3]=c0[3];
        p0[4]=c1[0]; p0[5]=c1[1]; p0[6]=c1[2]; p0[7]=c1[3];
        p1[0]=c2[0]; p1[1]=c2[1]; p1[2]=c2[2]; p1[3]=c2[3];
        p1[4]=c3[0]; p1[5]=c3[1]; p1[6]=c3[2]; p1[7]=c3[3];
        pa[jj][0] = p0;
        pa[jj][1] = p1;
      }

      // O += P V : V frag read once per pair
      __builtin_amdgcn_s_setprio(1);
#pragma unroll
      for (int k0 = 0; k0 < 2; ++k0)
#pragma unroll
        for (int nt = 0; nt < 4; ++nt) {
          bf16x8 bv = *(const bf16x8*)(Vc + (nt * 16 + l15) * 64 +
                                       (((k0 * 4 + quad) ^ vswz) * 8));
          if (actA) accO[ja][nt] = mfma16(pa[0][k0], bv, accO[ja][nt]);
          accO[jb][nt] = mfma16(pa[1][k0], bv, accO[jb][nt]);
        }
      __builtin_amdgcn_s_setprio(0);
    }

    cur ^= 1;
  }

  // finalize: reduce lp across quads (lanes sharing l15), permute to C-layout
#pragma unroll
  for (int j = 0; j < 4; ++j) {
    float lf = lp[j];
    lf += __shfl_xor(lf, 16);
    lf += __shfl_xor(lf, 32);           // all lanes: lf = l(qrow = l15)
    const int qb = qcs[j] * 64;
#pragma unroll
    for (int r = 0; r < 4; ++r) {
      float inv = 1.0f / __shfl(lf, quad * 4 + r);   // l for qrow = quad*4+r
#pragma unroll
      for (int nt = 0; nt < 4; ++nt) accO[j][nt][r] *= inv;
    }
#pragma unroll
    for (int nt = 0; nt < 4; ++nt) {
      bf16x4 ob = cvt4(accO[j][nt]);
#pragma unroll
      for (int r = 0; r < 4; ++r) {
        int sr = qb + w16 + quad * 4 + r;
        ao[((size_t)b * S_LEN + sr) * D_DIM + h * HDIM + nt * 16 + l15] = ob[r];
      }
    }
  }
}

// ---------------------------------------------------------------------------
// Output projection (pure bf16, XOR-swizzled): C = AO @ Wo^T + bo, fp32 out.
// XCD-chunked swizzle (512 = 8 * 64), order (x, y-fastest).
// ---------------------------------------------------------------------------
__global__ __launch_bounds__(256, 4) void out_gemm(
    const __bf16* __restrict__ Ain, const __bf16* __restrict__ Wbf,
    const float* __restrict__ bo, float* __restrict__ Cout)
{
  const int lin = blockIdx.x + (blockIdx.y << 6);   // 0..511
  const int wg  = (lin & 7) * 64 + (lin >> 3);
  const int xg  = wg >> 3;                          // 0..63
  const int yg  = wg & 7;                           // 0..7

  __shared__ __bf16 As[128 * 64];
  __shared__ __bf16 Bs[128 * 64];

  const int tid  = threadIdx.x;
  const int wave = tid >> 6;
  const int lane = tid & 63;
  const int l15  = lane & 15;
  const int quad = lane >> 4;
  const int mbase = xg * 128;
  const int nbase = yg * 128;
  const int wm = (wave & 1) * 64;
  const int wn = (wave >> 1) * 64;
  const int brow = lane >> 3;
  const int scol = ((lane & 7) ^ (brow & 7)) * 8;
  const int swz  = l15 & 7;

  f32x4 acc[4][4] = {};

  for (int kt = 0; kt < D_DIM; kt += 64) {
#pragma unroll
    for (int c = 0; c < 4; ++c) {
      int r = wave * 32 + c * 8 + brow;
      cp16(Ain + (size_t)(mbase + r) * D_DIM + kt + scol, As + r * 64);
      cp16(Wbf + (size_t)(nbase + r) * D_DIM + kt + scol, Bs + r * 64);
    }
    __syncthreads();

#pragma unroll
    for (int k0 = 0; k0 < 2; ++k0) {
      bf16x8 af[4], bfr[4];
#pragma unroll
      for (int i = 0; i < 4; ++i) {
        int off = ((k0 * 4 + quad) ^ swz) * 8;
        af[i]  = *(const bf16x8*)(As + (wm + i * 16 + l15) * 64 + off);
        bfr[i] = *(const bf16x8*)(Bs + (wn + i * 16 + l15) * 64 + off);
      }
#pragma unroll
      for (int mt = 0; mt < 4; ++mt)
#pragma unroll
        for (int nt = 0; nt < 4; ++nt)
          acc[mt][nt] = mfma16(af[mt], bfr[nt], acc[mt][nt]);
    }
    __syncthreads();
  }

#pragma unroll
  for (int mt = 0; mt < 4; ++mt)
#pragma unroll
    for (int nt = 0; nt < 4; ++nt) {
      int n = nbase + wn + nt * 16 + l15;
      float bb = bo[n];
      int m0 = mbase + wm + mt * 16 + quad * 4;
#pragma unroll
      for (int r = 0; r < 4; ++r)
        Cout[(size_t)(m0 + r) * D_DIM + n] = acc[mt][nt][r] + bb;
    }
}

extern "C" void kernel_launch(void* const* d_in, const int* in_sizes, int n_in,
                              void* d_out, int out_size, void* d_ws, size_t ws_size,
                              hipStream_t stream) {
  const float* q  = (const float*)d_in[0];
  const float* k  = (const float*)d_in[1];
  const float* v  = (const float*)d_in[2];
  // d_in[3]: causal mask — structure hard-coded
  const float* Wq = (const float*)d_in[4];
  const float* bq = (const float*)d_in[5];
  const float* Wk = (const float*)d_in[6];
  const float* bk = (const float*)d_in[7];
  const float* Wv = (const float*)d_in[8];
  const float* bv = (const float*)d_in[9];
  const float* Wo = (const float*)d_in[10];
  const float* bo = (const float*)d_in[11];

  __bf16* ws = (__bf16*)d_ws;
  const size_t WSZ = (size_t)D_DIM * D_DIM;          // 1048576
  const size_t NE  = (size_t)NB * S_LEN * D_DIM;     // 8388608
  __bf16* wbf = ws;                  // [0, 4M): 4 weight matrices bf16
  __bf16* qh  = ws + 4 * WSZ;
  __bf16* kh  = qh + NE;
  __bf16* vt  = kh + NE;             // [B,H,HD,S]
  __bf16* ao  = vt + NE;             // [B,S,D]
  __bf16* abf = vt + NE;             // aliases ao+ — dead before attn writes ao

  conv_all<<<dim3(8192, 4), 256, 0, stream>>>(q, k, v, Wq, Wk, Wv, Wo, abf, wbf);
  proj_bf16<<<dim3(64, 8, 3), 256, 0, stream>>>(abf, wbf, bq, bk, bv, qh, kh, vt);
  attn_kernel<<<dim3(8, 64), 256, 0, stream>>>(qh, kh, vt, ao);
  out_gemm<<<dim3(64, 8), 256, 0, stream>>>(ao, wbf + 3 * WSZ, bo, (float*)d_out);
}

// Round 10
// 304.530 us; speedup vs baseline: 1.0480x; 1.0480x over previous
//
#include <hip/hip_runtime.h>

#define S_LEN 2048
#define D_DIM 1024
#define NB    4
#define NH    16
#define HDIM  64
#define QSCL  0.18033688011112042f   // 0.125 * log2(e): softmax via exp2

typedef float  f32x4  __attribute__((ext_vector_type(4)));
typedef __bf16 bf16x4 __attribute__((ext_vector_type(4)));
typedef __bf16 bf16x8 __attribute__((ext_vector_type(8)));

static __device__ __forceinline__ f32x4 mfma16(bf16x8 a, bf16x8 b, f32x4 c) {
  return __builtin_amdgcn_mfma_f32_16x16x32_bf16(a, b, c, 0, 0, 0);
}
static __device__ __forceinline__ bf16x4 cvt4(f32x4 v) {
  return __builtin_convertvector(v, bf16x4);
}
// async 16B/lane global->LDS; LDS dest = wave-uniform base + lane*16
static __device__ __forceinline__ void cp16(const void* g, void* l) {
  __builtin_amdgcn_global_load_lds(
      (const __attribute__((address_space(1))) unsigned int*)g,
      (__attribute__((address_space(3))) unsigned int*)l, 16, 0, 0);
}

// ---------------------------------------------------------------------------
// Fused fp32 -> bf16 pre-convert for activations AND weights (R5-proven).
// grid = (8192, 4): y<3 -> q/k/v (8192 blocks x 1024 elems);
//                   y=3 -> Wq|Wk|Wv|Wo (x<4096, 1024 blocks each).
// ---------------------------------------------------------------------------
__global__ __launch_bounds__(256) void conv_all(
    const float* __restrict__ q, const float* __restrict__ k,
    const float* __restrict__ v,
    const float* __restrict__ Wq, const float* __restrict__ Wk,
    const float* __restrict__ Wv, const float* __restrict__ Wo,
    __bf16* __restrict__ abf, __bf16* __restrict__ wbf)
{
  const int y = blockIdx.y;
  if (y < 3) {
    const float* src = (y == 0) ? q : (y == 1) ? k : v;
    size_t i = ((size_t)blockIdx.x * 256 + threadIdx.x) * 4;
    f32x4 x = *(const f32x4*)(src + i);
    *(bf16x4*)(abf + (size_t)y * ((size_t)NB * S_LEN * D_DIM) + i) = cvt4(x);
  } else {
    if (blockIdx.x >= 4096) return;
    const int w = blockIdx.x >> 10;             // which weight matrix
    const float* src = (w == 0) ? Wq : (w == 1) ? Wk : (w == 2) ? Wv : Wo;
    size_t i = ((size_t)(blockIdx.x & 1023) * 256 + threadIdx.x) * 4;
    f32x4 x = *(const f32x4*)(src + i);
    *(bf16x4*)(wbf + (size_t)w * (D_DIM * D_DIM) + i) = cvt4(x);
  }
}

// ---------------------------------------------------------------------------
// Shared epilogue for QKV projection: scatter to head layout.
// ---------------------------------------------------------------------------
static __device__ __forceinline__ void proj_epilogue(
    f32x4 (&acc)[4][4], int z, int mbase, int nbase, int wm, int wn,
    int l15, int quad, const float* bias,
    __bf16* qh, __bf16* kh, __bf16* vt)
{
  const float scl = (z == 0) ? QSCL : 1.0f;  // fold 1/sqrt(HD)*log2e into Q
#pragma unroll
  for (int mt = 0; mt < 4; ++mt)
#pragma unroll
    for (int nt = 0; nt < 4; ++nt) {
      int n = nbase + wn + nt * 16 + l15;
      int h = n >> 6, hd = n & 63;
      float bb = bias[n];
      f32x4 vv = acc[mt][nt];
#pragma unroll
      for (int r = 0; r < 4; ++r) vv[r] = (vv[r] + bb) * scl;
      bf16x4 pv = cvt4(vv);
      int m0 = mbase + wm + mt * 16 + quad * 4;
      int b = m0 >> 11, s0 = m0 & 2047;
      if (z == 2) {
        *(bf16x4*)(vt + ((size_t)((b * NH + h) * HDIM + hd)) * S_LEN + s0) = pv;
      } else {
        __bf16* out = (z == 0) ? qh : kh;
#pragma unroll
        for (int r = 0; r < 4; ++r)
          out[((size_t)(b * NH + h) * S_LEN + s0 + r) * HDIM + hd] = pv[r];
      }
    }
}

// ---------------------------------------------------------------------------
// QKV projection, pure-bf16: 128x128, BK=64, XOR-swizzled async staging.
// R8-measured: 61us, MfmaUtil 36%, FETCH 42.5MB, 0 conflicts (T1 confirmed).
// XCD-chunked swizzle: each XCD gets 192 contiguous wgs, (z, x, y-fastest).
// ---------------------------------------------------------------------------
__global__ __launch_bounds__(256, 4) void proj_bf16(
    const __bf16* __restrict__ abf, const __bf16* __restrict__ Wbf,
    const float* __restrict__ bq, const float* __restrict__ bk, const float* __restrict__ bv,
    __bf16* __restrict__ qh, __bf16* __restrict__ kh, __bf16* __restrict__ vt)
{
  const int lin = blockIdx.x + (blockIdx.y << 6) + (blockIdx.z << 9); // 0..1535
  const int wg  = (lin & 7) * 192 + (lin >> 3);
  const int z   = wg >> 9;            // 0..2
  const int rem = wg & 511;
  const int xg  = rem >> 3;           // 0..63
  const int yg  = rem & 7;            // 0..7

  const __bf16* A = abf + (size_t)z * ((size_t)NB * S_LEN * D_DIM);
  const __bf16* W = Wbf + (size_t)z * (D_DIM * D_DIM);
  const float* bias = (z == 0) ? bq : (z == 1) ? bk : bv;

  __shared__ __bf16 As[128 * 64];
  __shared__ __bf16 Bs[128 * 64];

  const int tid  = threadIdx.x;
  const int wave = tid >> 6;
  const int lane = tid & 63;
  const int l15  = lane & 15;
  const int quad = lane >> 4;
  const int mbase = xg * 128;
  const int nbase = yg * 128;
  const int wm = (wave & 1) * 64;
  const int wn = (wave >> 1) * 64;
  const int brow = lane >> 3;
  const int scol = ((lane & 7) ^ (brow & 7)) * 8;
  const int swz  = l15 & 7;

  f32x4 acc[4][4] = {};

  for (int kt = 0; kt < D_DIM; kt += 64) {
#pragma unroll
    for (int c = 0; c < 4; ++c) {
      int r = wave * 32 + c * 8 + brow;
      cp16(A + (size_t)(mbase + r) * D_DIM + kt + scol, As + r * 64);
      cp16(W + (size_t)(nbase + r) * D_DIM + kt + scol, Bs + r * 64);
    }
    __syncthreads();

#pragma unroll
    for (int k0 = 0; k0 < 2; ++k0) {
      bf16x8 af[4], bfr[4];
#pragma unroll
      for (int i = 0; i < 4; ++i) {
        int off = ((k0 * 4 + quad) ^ swz) * 8;
        af[i]  = *(const bf16x8*)(As + (wm + i * 16 + l15) * 64 + off);
        bfr[i] = *(const bf16x8*)(Bs + (wn + i * 16 + l15) * 64 + off);
      }
#pragma unroll
      for (int mt = 0; mt < 4; ++mt)
#pragma unroll
        for (int nt = 0; nt < 4; ++nt)
          acc[mt][nt] = mfma16(af[mt], bfr[nt], acc[mt][nt]);
    }
    __syncthreads();
  }

  proj_epilogue(acc, z, mbase, nbase, wm, wn, l15, quad, bias, qh, kh, vt);
}

// ---------------------------------------------------------------------------
// Flash attention: 2 causal-paired chunks/block, TRANSPOSE-FREE P.
// R8-proven optimum of this family (R9's 4-chunk/2-blocks-per-CU regressed:
// occupancy is the binding constraint). grid (16,64) = 1024 blocks = 4/CU;
// LDS 32KB (K/V dbuf only). QK^T A-tile (K-frag) rows PERMUTED so the MFMA
// emits P directly in PV A-frag order (zero cross-lane ops, zero P-LDS).
// Stage swizzle h(row)=4*((row>>3)&1)+(row&3) keeps the permuted K-read
// (col xor l15&7) and the linear V-read (col xor ((l15>>3)<<2)|(l15&3))
// conflict-free. K/V double-buffered, one barrier/tile. XCD swizzle: 8
// complete bh per XCD (4MB = one L2). s_setprio(1) wraps MFMA clusters.
// ---------------------------------------------------------------------------
__global__ __launch_bounds__(256, 4) void attn_kernel(
    const __bf16* __restrict__ qh, const __bf16* __restrict__ kh,
    const __bf16* __restrict__ vt, __bf16* __restrict__ ao)
{
  __shared__ __bf16 Kb[2][64 * 64];
  __shared__ __bf16 Vb[2][64 * 64];

  // XCD-bijective swizzle: lin%8 == XCD; each XCD gets 8 complete bh.
  const int lin = blockIdx.x + (blockIdx.y << 4);      // 0..1023
  const int xcd = lin & 7;
  const int idx = lin >> 3;                            // 0..127
  const int u   = idx & 15;
  const int x   = (u & 1) ? (15 - (u >> 1)) : (u >> 1);  // 0,15,1,14,... balanced
  const int bh  = xcd * 8 + (idx >> 4);                // 8 bh per XCD

  const int qc0 = x, qc1 = 31 - x;                     // causal pair
  const int last = qc1;

  const __bf16* qp = qh + (size_t)bh * S_LEN * HDIM;
  const __bf16* kp = kh + (size_t)bh * S_LEN * HDIM;
  const __bf16* vp = vt + (size_t)bh * HDIM * S_LEN;

  const int tid  = threadIdx.x;
  const int wave = tid >> 6;
  const int lane = tid & 63;
  const int l15  = lane & 15;
  const int quad = lane >> 4;
  const int w16  = wave * 16;
  const int srow = lane >> 3;
  const int swz  = l15 & 7;                            // K-read col swizzle
  const int vswz = ((l15 >> 3) << 2) | (l15 & 3);      // V-read col swizzle
  const int kr0  = ((l15 >> 2) << 3) | (l15 & 3);      // K-frag row base (perm)
  const int b = bh >> 4, h = bh & 15;

  // Q fragments (B-op layout: col=l15, k=quad*8+j)
  bf16x8 fq[2][2];
#pragma unroll
  for (int j = 0; j < 2; ++j) {
    const int qb = (j ? qc1 : qc0) * 64;
    const __bf16* qrow = qp + (size_t)(qb + w16 + l15) * HDIM;
    fq[j][0] = *(const bf16x8*)(qrow + quad * 8);
    fq[j][1] = *(const bf16x8*)(qrow + 32 + quad * 8);
  }

  f32x4 accO[2][4] = {};
  float lp[2] = {0.f, 0.f};   // per-lane partial denom, qrow = l15

  // prologue: stage tile 0 into buffer 0.  h(row)=4*((row>>3)&1)+(row&3):
  // row = w16+8c+srow -> h = 4*(c&1) + (srow&3).
#pragma unroll
  for (int c = 0; c < 2; ++c) {
    int rb = w16 + c * 8;
    int sc2 = (((lane & 7) ^ (((c & 1) << 2) | (srow & 3)))) * 8;
    cp16(kp + (size_t)(rb + srow) * HDIM + sc2, &Kb[0][rb * 64]);
    cp16(vp + (size_t)(rb + srow) * S_LEN + sc2, &Vb[0][rb * 64]);
  }

  int cur = 0;
  for (int kt = 0; kt <= last; ++kt) {
    __syncthreads();   // drains own vmcnt -> buf[cur] staged; buf[cur^1] free

    if (kt < last) {   // stage kt+1 into the free buffer; hidden under compute
#pragma unroll
      for (int c = 0; c < 2; ++c) {
        int rb = w16 + c * 8;
        int sc2 = (((lane & 7) ^ (((c & 1) << 2) | (srow & 3)))) * 8;
        cp16(kp + (size_t)((kt + 1) * 64 + rb + srow) * HDIM + sc2,
             &Kb[cur ^ 1][rb * 64]);
        cp16(vp + (size_t)(rb + srow) * S_LEN + (kt + 1) * 64 + sc2,
             &Vb[cur ^ 1][rb * 64]);
      }
    }

    const __bf16* Kc = &Kb[cur][0];
    const __bf16* Vc = &Vb[cur][0];
    const bool act0 = (kt <= qc0);   // block-uniform

    // S^T = K Q^T with PERMUTED K-frag rows; K frag read once, both chunks
    f32x4 sc[2][4] = {};
    __builtin_amdgcn_s_setprio(1);
#pragma unroll
    for (int k0 = 0; k0 < 2; ++k0)
#pragma unroll
      for (int nt = 0; nt < 4; ++nt) {
        const int krow = kr0 + ((nt & 1) << 2) + ((nt >> 1) << 5);
        bf16x8 bk = *(const bf16x8*)(Kc + krow * 64 +
                                     (((k0 * 4 + quad) ^ swz) * 8));
        if (act0) sc[0][nt] = mfma16(bk, fq[0][k0], sc[0][nt]);
        sc[1][nt] = mfma16(bk, fq[1][k0], sc[1][nt]);
      }
    __builtin_amdgcn_s_setprio(0);

    // softmax -> PV A-frags, pure register (no transpose needed)
    bf16x8 pa[2][2];
#pragma unroll
    for (int j = 0; j < 2; ++j) {
      if (j == 0 && !act0) continue;   // uniform
      const int qcj = j ? qc1 : qc0;
      f32x4 pf[4];
#pragma unroll
      for (int nt = 0; nt < 4; ++nt) {
#pragma unroll
        for (int r = 0; r < 4; ++r) pf[nt][r] = __builtin_amdgcn_exp2f(sc[j][nt][r]);
        if (kt == qcj) {  // diag tile: causal mask (relabeled key)
#pragma unroll
          for (int r = 0; r < 4; ++r) {
            int key = ((nt >> 1) << 5) + (quad << 3) + ((nt & 1) << 2) + r;
            if (key > w16 + l15) pf[nt][r] = 0.f;
          }
        }
      }
      f32x4 lv = (pf[0] + pf[1]) + (pf[2] + pf[3]);
      lp[j] += (lv[0] + lv[1]) + (lv[2] + lv[3]);
      bf16x4 c0 = cvt4(pf[0]), c1 = cvt4(pf[1]), c2 = cvt4(pf[2]), c3 = cvt4(pf[3]);
      bf16x8 p0, p1;
      p0[0]=c0[0]; p0[1]=c0[1]; p0[2]=c0[2]; p0[3]=c0[3];
      p0[4]=c1[0]; p0[5]=c1[1]; p0[6]=c1[2]; p0[7]=c1[3];
      p1[0]=c2[0]; p1[1]=c2[1]; p1[2]=c2[2]; p1[3]=c2[3];
      p1[4]=c3[0]; p1[5]=c3[1]; p1[6]=c3[2]; p1[7]=c3[3];
      pa[j][0] = p0;
      pa[j][1] = p1;
    }

    // O += P V : V frag read once, feeds both chunks
    __builtin_amdgcn_s_setprio(1);
#pragma unroll
    for (int k0 = 0; k0 < 2; ++k0)
#pragma unroll
      for (int nt = 0; nt < 4; ++nt) {
        bf16x8 bv = *(const bf16x8*)(Vc + (nt * 16 + l15) * 64 +
                                     (((k0 * 4 + quad) ^ vswz) * 8));
        if (act0) accO[0][nt] = mfma16(pa[0][k0], bv, accO[0][nt]);
        accO[1][nt] = mfma16(pa[1][k0], bv, accO[1][nt]);
      }
    __builtin_amdgcn_s_setprio(0);

    cur ^= 1;
  }

  // finalize: reduce lp across quads (lanes sharing l15), permute to C-layout
#pragma unroll
  for (int j = 0; j < 2; ++j) {
    float lf = lp[j];
    lf += __shfl_xor(lf, 16);
    lf += __shfl_xor(lf, 32);           // all lanes: lf = l(qrow = l15)
    const int qb = (j ? qc1 : qc0) * 64;
#pragma unroll
    for (int r = 0; r < 4; ++r) {
      float inv = 1.0f / __shfl(lf, quad * 4 + r);   // l for qrow = quad*4+r
#pragma unroll
      for (int nt = 0; nt < 4; ++nt) accO[j][nt][r] *= inv;
    }
#pragma unroll
    for (int nt = 0; nt < 4; ++nt) {
      bf16x4 ob = cvt4(accO[j][nt]);
#pragma unroll
      for (int r = 0; r < 4; ++r) {
        int sr = qb + w16 + quad * 4 + r;
        ao[((size_t)b * S_LEN + sr) * D_DIM + h * HDIM + nt * 16 + l15] = ob[r];
      }
    }
  }
}

// ---------------------------------------------------------------------------
// Output projection (pure bf16, XOR-swizzled): C = AO @ Wo^T + bo, fp32 out.
// XCD-chunked swizzle (512 = 8 * 64), order (x, y-fastest).
// ---------------------------------------------------------------------------
__global__ __launch_bounds__(256, 4) void out_gemm(
    const __bf16* __restrict__ Ain, const __bf16* __restrict__ Wbf,
    const float* __restrict__ bo, float* __restrict__ Cout)
{
  const int lin = blockIdx.x + (blockIdx.y << 6);   // 0..511
  const int wg  = (lin & 7) * 64 + (lin >> 3);
  const int xg  = wg >> 3;                          // 0..63
  const int yg  = wg & 7;                           // 0..7

  __shared__ __bf16 As[128 * 64];
  __shared__ __bf16 Bs[128 * 64];

  const int tid  = threadIdx.x;
  const int wave = tid >> 6;
  const int lane = tid & 63;
  const int l15  = lane & 15;
  const int quad = lane >> 4;
  const int mbase = xg * 128;
  const int nbase = yg * 128;
  const int wm = (wave & 1) * 64;
  const int wn = (wave >> 1) * 64;
  const int brow = lane >> 3;
  const int scol = ((lane & 7) ^ (brow & 7)) * 8;
  const int swz  = l15 & 7;

  f32x4 acc[4][4] = {};

  for (int kt = 0; kt < D_DIM; kt += 64) {
#pragma unroll
    for (int c = 0; c < 4; ++c) {
      int r = wave * 32 + c * 8 + brow;
      cp16(Ain + (size_t)(mbase + r) * D_DIM + kt + scol, As + r * 64);
      cp16(Wbf + (size_t)(nbase + r) * D_DIM + kt + scol, Bs + r * 64);
    }
    __syncthreads();

#pragma unroll
    for (int k0 = 0; k0 < 2; ++k0) {
      bf16x8 af[4], bfr[4];
#pragma unroll
      for (int i = 0; i < 4; ++i) {
        int off = ((k0 * 4 + quad) ^ swz) * 8;
        af[i]  = *(const bf16x8*)(As + (wm + i * 16 + l15) * 64 + off);
        bfr[i] = *(const bf16x8*)(Bs + (wn + i * 16 + l15) * 64 + off);
      }
#pragma unroll
      for (int mt = 0; mt < 4; ++mt)
#pragma unroll
        for (int nt = 0; nt < 4; ++nt)
          acc[mt][nt] = mfma16(af[mt], bfr[nt], acc[mt][nt]);
    }
    __syncthreads();
  }

#pragma unroll
  for (int mt = 0; mt < 4; ++mt)
#pragma unroll
    for (int nt = 0; nt < 4; ++nt) {
      int n = nbase + wn + nt * 16 + l15;
      float bb = bo[n];
      int m0 = mbase + wm + mt * 16 + quad * 4;
#pragma unroll
      for (int r = 0; r < 4; ++r)
        Cout[(size_t)(m0 + r) * D_DIM + n] = acc[mt][nt][r] + bb;
    }
}

extern "C" void kernel_launch(void* const* d_in, const int* in_sizes, int n_in,
                              void* d_out, int out_size, void* d_ws, size_t ws_size,
                              hipStream_t stream) {
  const float* q  = (const float*)d_in[0];
  const float* k  = (const float*)d_in[1];
  const float* v  = (const float*)d_in[2];
  // d_in[3]: causal mask — structure hard-coded
  const float* Wq = (const float*)d_in[4];
  const float* bq = (const float*)d_in[5];
  const float* Wk = (const float*)d_in[6];
  const float* bk = (const float*)d_in[7];
  const float* Wv = (const float*)d_in[8];
  const float* bv = (const float*)d_in[9];
  const float* Wo = (const float*)d_in[10];
  const float* bo = (const float*)d_in[11];

  __bf16* ws = (__bf16*)d_ws;
  const size_t WSZ = (size_t)D_DIM * D_DIM;          // 1048576
  const size_t NE  = (size_t)NB * S_LEN * D_DIM;     // 8388608
  __bf16* wbf = ws;                  // [0, 4M): 4 weight matrices bf16
  __bf16* qh  = ws + 4 * WSZ;
  __bf16* kh  = qh + NE;
  __bf16* vt  = kh + NE;             // [B,H,HD,S]
  __bf16* ao  = vt + NE;             // [B,S,D]
  __bf16* abf = vt + NE;             // aliases ao+ — dead before attn writes ao

  conv_all<<<dim3(8192, 4), 256, 0, stream>>>(q, k, v, Wq, Wk, Wv, Wo, abf, wbf);
  proj_bf16<<<dim3(64, 8, 3), 256, 0, stream>>>(abf, wbf, bq, bk, bv, qh, kh, vt);
  attn_kernel<<<dim3(16, 64), 256, 0, stream>>>(qh, kh, vt, ao);
  out_gemm<<<dim3(64, 8), 256, 0, stream>>>(ao, wbf + 3 * WSZ, bo, (float*)d_out);
}